// Round 1
// baseline (191.354 us; speedup 1.0000x reference)
//
#include <hip/hip_runtime.h>
#include <hip/hip_bf16.h>

#define T_LEN 200
#define TP    208        // padded rows (13 * 16)
#define MT    13

typedef __bf16 bf16x8 __attribute__((ext_vector_type(8)));
typedef float  f32x4  __attribute__((ext_vector_type(4)));

struct __align__(16) Smem {
  unsigned char behL[TP * 128];   // 208 x 64 bf16, swizzled
  unsigned char h1L [TP * 128];   // 208 x 64 bf16, swizzled
  unsigned char w1T [64 * 128];   // W1eff^T [j][d] bf16, swizzled
  unsigned char w2T [32 * 128];   // W2^T    [j2][j1] bf16, swizzled
  float candL[64];
  float bias1L[64];
  float biasPart[4][64];
  float logitP[2][TP];
  float wts[TP];
  float part4[4][64];
  float red[8];
  int   flag;                      // 1 => mask stored as bytes (bool), 0 => int32
};

__device__ __forceinline__ int swz(int row, int byte_off) {
  return byte_off ^ ((row & 7) << 4);
}

__global__ __launch_bounds__(256) void lau_kernel(
    const float* __restrict__ behG, const float* __restrict__ candG,
    const int*  __restrict__ maskG,
    const float* __restrict__ W1g, const float* __restrict__ b1g, const float* __restrict__ a1g,
    const float* __restrict__ W2g, const float* __restrict__ b2g, const float* __restrict__ a2g,
    const float* __restrict__ W3g, const float* __restrict__ b3g,
    float* __restrict__ outG)
{
  __shared__ Smem s;
  const int tid  = threadIdx.x;
  const int lane = tid & 63;
  const int wv   = tid >> 6;
  const int b    = blockIdx.x;

  // ---- phase 0: candidate row + mask dtype detection ----
  int boolish = 0;
  if (tid < 64) {
    s.candL[tid] = candG[(size_t)b * 64 + tid];
    boolish = (((const unsigned int*)maskG)[tid] > 1u) ? 1 : 0; // first 256B, safe in both modes
  }
  if (tid == 0) s.flag = 0;
  __syncthreads();
  if (boolish) s.flag = 1; // benign same-value race

  // ---- phase 1a: stage behavior f32 -> bf16 into swizzled LDS ----
  {
    f32x4 xa[7], xb[7];
#pragma unroll
    for (int k = 0; k < 7; ++k) {
      xa[k] = f32x4{0.f, 0.f, 0.f, 0.f};
      xb[k] = f32x4{0.f, 0.f, 0.f, 0.f};
      int c = tid + k * 256;
      int row = c >> 3, c16 = c & 7;
      if (c < TP * 8 && row < T_LEN) {
        const float* p = behG + ((size_t)b * T_LEN + row) * 64 + c16 * 8;
        xa[k] = *(const f32x4*)p;
        xb[k] = *(const f32x4*)(p + 4);
      }
    }
#pragma unroll
    for (int k = 0; k < 7; ++k) {
      int c = tid + k * 256;
      if (c < TP * 8) {
        int row = c >> 3, c16 = c & 7;
        bf16x8 hv;
        hv[0] = (__bf16)xa[k][0]; hv[1] = (__bf16)xa[k][1];
        hv[2] = (__bf16)xa[k][2]; hv[3] = (__bf16)xa[k][3];
        hv[4] = (__bf16)xb[k][0]; hv[5] = (__bf16)xb[k][1];
        hv[6] = (__bf16)xb[k][2]; hv[7] = (__bf16)xb[k][3];
        *(bf16x8*)(s.behL + swz(row, row * 128 + c16 * 16)) = hv;
      }
    }
  }

  // ---- phase 1b: W1eff^T = (W1a + W1c + cand_d * W1d)^T  (bf16, swizzled) ----
  for (int idx = tid; idx < 4096; idx += 256) {
    int j = idx >> 6, d = idx & 63;
    float v = W1g[d * 64 + j] + W1g[(128 + d) * 64 + j] + s.candL[d] * W1g[(192 + d) * 64 + j];
    *(__bf16*)(s.w1T + swz(j, j * 128 + d * 2)) = (__bf16)v;
  }
  // W2^T
  for (int idx = tid; idx < 2048; idx += 256) {
    int j2 = idx >> 6, j1 = idx & 63;
    *(__bf16*)(s.w2T + swz(j2, j2 * 128 + j1 * 2)) = (__bf16)W2g[j1 * 32 + j2];
  }
  // bias1eff partials: b1 + sum_d cand_d * (W1b - W1c)
  {
    int j = tid & 63, part = tid >> 6;
    float acc = 0.f;
#pragma unroll
    for (int dd = 0; dd < 16; ++dd) {
      int d = part * 16 + dd;
      acc += s.candL[d] * (W1g[(64 + d) * 64 + j] - W1g[(128 + d) * 64 + j]);
    }
    s.biasPart[part][j] = acc;
  }
  __syncthreads();
  if (tid < 64)
    s.bias1L[tid] = b1g[tid] + s.biasPart[0][tid] + s.biasPart[1][tid]
                  + s.biasPart[2][tid] + s.biasPart[3][tid];
  __syncthreads();

  // ---- phase 2: layer 1 MFMA  h1 = prelu(beh @ W1eff + bias1eff) ----
  {
    const int col = (wv << 4) + (lane & 15);
    const int kb  = (lane >> 4) << 3;
    bf16x8 bfr0 = *(const bf16x8*)(s.w1T + swz(col, col * 128 + kb * 2));
    bf16x8 bfr1 = *(const bf16x8*)(s.w1T + swz(col, col * 128 + (kb + 32) * 2));
    const float bias = s.bias1L[col];
    const float al1  = a1g[0];
#pragma unroll
    for (int mt = 0; mt < MT; ++mt) {
      int row = (mt << 4) + (lane & 15);
      bf16x8 a0 = *(const bf16x8*)(s.behL + swz(row, row * 128 + kb * 2));
      bf16x8 a1 = *(const bf16x8*)(s.behL + swz(row, row * 128 + (kb + 32) * 2));
      f32x4 acc = {0.f, 0.f, 0.f, 0.f};
      acc = __builtin_amdgcn_mfma_f32_16x16x32_bf16(a0, bfr0, acc, 0, 0, 0);
      acc = __builtin_amdgcn_mfma_f32_16x16x32_bf16(a1, bfr1, acc, 0, 0, 0);
#pragma unroll
      for (int i = 0; i < 4; ++i) {
        float h = acc[i] + bias;
        h = (h >= 0.f) ? h : al1 * h;
        int ro = (mt << 4) + ((lane >> 4) << 2) + i;   // C/D: col=lane&15, row=(lane>>4)*4+i
        *(__bf16*)(s.h1L + swz(ro, ro * 128 + col * 2)) = (__bf16)h;
      }
    }
  }
  __syncthreads();

  // ---- phase 3: layer 2 MFMA + layer 3 dot -> partial logits ----
  {
    const float al2 = a2g[0];
    for (int job = wv; job < 26; job += 4) {
      int mt = job >> 1, nt = job & 1;
      int col = (nt << 4) + (lane & 15);
      int kb  = (lane >> 4) << 3;
      bf16x8 bfr0 = *(const bf16x8*)(s.w2T + swz(col, col * 128 + kb * 2));
      bf16x8 bfr1 = *(const bf16x8*)(s.w2T + swz(col, col * 128 + (kb + 32) * 2));
      int row = (mt << 4) + (lane & 15);
      bf16x8 a0 = *(const bf16x8*)(s.h1L + swz(row, row * 128 + kb * 2));
      bf16x8 a1 = *(const bf16x8*)(s.h1L + swz(row, row * 128 + (kb + 32) * 2));
      f32x4 acc = {0.f, 0.f, 0.f, 0.f};
      acc = __builtin_amdgcn_mfma_f32_16x16x32_bf16(a0, bfr0, acc, 0, 0, 0);
      acc = __builtin_amdgcn_mfma_f32_16x16x32_bf16(a1, bfr1, acc, 0, 0, 0);
      float bb2 = b2g[col];
      float w3v = W3g[col];
      f32x4 p;
#pragma unroll
      for (int i = 0; i < 4; ++i) {
        float h = acc[i] + bb2;
        h = (h >= 0.f) ? h : al2 * h;
        p[i] = h * w3v;
      }
#pragma unroll
      for (int off = 1; off < 16; off <<= 1) {
#pragma unroll
        for (int i = 0; i < 4; ++i) p[i] += __shfl_xor(p[i], off);
      }
      if ((lane & 15) == 0) {
#pragma unroll
        for (int i = 0; i < 4; ++i)
          s.logitP[nt][(mt << 4) + ((lane >> 4) << 2) + i] = p[i];
      }
    }
  }
  __syncthreads();

  // ---- phase 4: masked softmax over T ----
  {
    const float NEGINF = -__builtin_inff();
    float lg = NEGINF;
    bool valid = false;
    int t = tid;
    if (t < T_LEN) {
      int mv = s.flag ? (int)((const unsigned char*)maskG)[(size_t)b * T_LEN + t]
                      : maskG[(size_t)b * T_LEN + t];
      valid = (mv != 0);
      if (valid) lg = s.logitP[0][t] + s.logitP[1][t] + b3g[0];
    }
    float m = lg;
#pragma unroll
    for (int off = 1; off < 64; off <<= 1) m = fmaxf(m, __shfl_xor(m, off));
    if (lane == 0) s.red[wv] = m;
    __syncthreads();
    m = fmaxf(fmaxf(s.red[0], s.red[1]), fmaxf(s.red[2], s.red[3]));
    float e = valid ? __expf(lg - m) : 0.f;
    float sum = e;
#pragma unroll
    for (int off = 1; off < 64; off <<= 1) sum += __shfl_xor(sum, off);
    if (lane == 0) s.red[4 + wv] = sum;
    __syncthreads();
    sum = s.red[4] + s.red[5] + s.red[6] + s.red[7];
    float winv = 1.f / sum;
    if (t < TP) s.wts[t] = (t < T_LEN) ? e * winv : 0.f;
  }
  __syncthreads();

  // ---- phase 5: out[b,d] = sum_t w[t] * beh[t,d]  (beh from LDS bf16) ----
  {
    float acc = 0.f;
    for (int t = wv; t < T_LEN; t += 4) {
      float wt = s.wts[t];
      float x = (float)*(const __bf16*)(s.behL + swz(t, t * 128 + lane * 2));
      acc += wt * x;
    }
    s.part4[wv][lane] = acc;
  }
  __syncthreads();
  if (tid < 64) {
    float o = s.part4[0][tid] + s.part4[1][tid] + s.part4[2][tid] + s.part4[3][tid];
    outG[(size_t)b * 64 + tid] = o;
  }
}

extern "C" void kernel_launch(void* const* d_in, const int* in_sizes, int n_in,
                              void* d_out, int out_size, void* d_ws, size_t ws_size,
                              hipStream_t stream) {
  (void)n_in; (void)d_ws; (void)ws_size; (void)out_size;
  const float* beh  = (const float*)d_in[0];
  const float* cand = (const float*)d_in[1];
  const int*   mask = (const int*)d_in[2];
  const float* W1   = (const float*)d_in[3];
  const float* b1   = (const float*)d_in[4];
  const float* a1   = (const float*)d_in[5];
  const float* W2   = (const float*)d_in[6];
  const float* b2   = (const float*)d_in[7];
  const float* a2   = (const float*)d_in[8];
  const float* W3   = (const float*)d_in[9];
  const float* b3   = (const float*)d_in[10];
  int B = in_sizes[1] / 64;   // 4096
  lau_kernel<<<B, 256, 0, stream>>>(beh, cand, mask, W1, b1, a1, W2, b2, a2, W3, b3,
                                    (float*)d_out);
}

// Round 2
// 106.216 us; speedup vs baseline: 1.8016x; 1.8016x over previous
//
#include <hip/hip_runtime.h>
#include <hip/hip_bf16.h>

#define T_LEN 200
#define MT    13          // ceil(200/16)

typedef __bf16 bf16x8 __attribute__((ext_vector_type(8)));
typedef float  f32x4  __attribute__((ext_vector_type(4)));

struct __align__(16) Smem {
  unsigned char w1T[64 * 256];     // [j][k0..127] bf16, swz; k<64: W1a+W1c, k>=64: W1d
  unsigned char w2T[32 * 128];     // [j2][j1] bf16, swz
  unsigned char h1T[4][16 * 128];  // per-wave transpose tile [row][col] bf16, swz
  float candL[4][64];
  float wts16[4][16];
  float outL[4][64];
};

__device__ __forceinline__ void loadA(const float* __restrict__ behB, int t, int kb,
                                      f32x4* x) {
  if (t < T_LEN) {
    const float* p = behB + (size_t)t * 64 + kb;
    x[0] = *(const f32x4*)p;
    x[1] = *(const f32x4*)(p + 4);
    x[2] = *(const f32x4*)(p + 32);
    x[3] = *(const f32x4*)(p + 36);
  } else {
    x[0] = f32x4{0.f, 0.f, 0.f, 0.f};
    x[1] = f32x4{0.f, 0.f, 0.f, 0.f};
    x[2] = f32x4{0.f, 0.f, 0.f, 0.f};
    x[3] = f32x4{0.f, 0.f, 0.f, 0.f};
  }
}

__global__ __launch_bounds__(256, 3) void lau_kernel(
    const float* __restrict__ behG, const float* __restrict__ candG,
    const int*  __restrict__ maskG,
    const float* __restrict__ W1g, const float* __restrict__ b1g, const float* __restrict__ a1g,
    const float* __restrict__ W2g, const float* __restrict__ b2g, const float* __restrict__ a2g,
    const float* __restrict__ W3g, const float* __restrict__ b3g,
    float* __restrict__ outG)
{
  __shared__ Smem s;
  const int tid  = threadIdx.x;
  const int lane = tid & 63;
  const int wv   = tid >> 6;
  const int b    = blockIdx.x * 4 + wv;

  // ---- cooperative weight staging (batch-independent) ----
  for (int idx = tid; idx < 8192; idx += 256) {
    int j = idx & 63, k = idx >> 6;
    float v = (k < 64) ? (W1g[k * 64 + j] + W1g[(128 + k) * 64 + j])
                       : W1g[(128 + k) * 64 + j];           // 192+(k-64)
    *(__bf16*)(s.w1T + ((j * 256 + k * 2) ^ ((j & 7) << 4))) = (__bf16)v;
  }
  for (int idx = tid; idx < 2048; idx += 256) {
    int j2 = idx & 31, j1 = idx >> 5;
    *(__bf16*)(s.w2T + ((j2 * 128 + j1 * 2) ^ ((j2 & 7) << 4))) = (__bf16)W2g[j1 * 32 + j2];
  }
  s.candL[wv][lane] = candG[(size_t)b * 64 + lane];
  __syncthreads();
  // ---- waves are fully independent from here ----

  const int r  = lane & 15;        // row within 16-tile / output col within n-tile
  const int g  = lane >> 4;        // k-subgroup
  const int kb = g * 8;

  // mask dtype detection (per wave, uniform)
  const bool boolmask = (__ballot(((const unsigned int*)maskG)[lane] > 1u) != 0ull);

  // cand chunks for this lane's k-columns
  f32x4 c0a = *(const f32x4*)&s.candL[wv][kb];
  f32x4 c0b = *(const f32x4*)&s.candL[wv][kb + 4];
  f32x4 c1a = *(const f32x4*)&s.candL[wv][kb + 32];
  f32x4 c1b = *(const f32x4*)&s.candL[wv][kb + 36];

  // bias1eff[lane] = b1[lane] + sum_d cand_d * (W1b[d][lane] - W1c[d][lane])
  float bias = b1g[lane];
#pragma unroll 8
  for (int d = 0; d < 64; ++d) {
    float cd = s.candL[wv][d];
    bias += cd * (W1g[(64 + d) * 64 + lane] - W1g[(128 + d) * 64 + lane]);
  }
  float bias_nt[4];
#pragma unroll
  for (int nt = 0; nt < 4; ++nt) bias_nt[nt] = __shfl(bias, nt * 16 + r);

  const float al1 = a1g[0];
  const float al2 = a2g[0];
  const float b2v0 = b2g[r],      b2v1 = b2g[16 + r];
  const float w3v0 = W3g[r],      w3v1 = W3g[16 + r];
  (void)b3g; // constant bias cancels in softmax

  // hoist layer-2 B fragments (K=64, N=32)
  bf16x8 B2[2][2];
#pragma unroll
  for (int nt2 = 0; nt2 < 2; ++nt2)
#pragma unroll
    for (int kc = 0; kc < 2; ++kc) {
      int j2 = nt2 * 16 + r;
      B2[nt2][kc] = *(const bf16x8*)(s.w2T +
          ((j2 * 128 + (kb + 32 * kc) * 2) ^ ((j2 & 7) << 4)));
    }

  const float* behB = behG + (size_t)b * T_LEN * 64;
  const unsigned char* maskB8 = (const unsigned char*)maskG + (size_t)b * T_LEN;
  const int* maskB32 = maskG + (size_t)b * T_LEN;

  // online-softmax state + fused weighted-sum accumulators (this lane's 16 cols)
  float mrun = -__builtin_inff();
  float srun = 0.f;
  f32x4 o0 = {0,0,0,0}, o1 = {0,0,0,0}, o2 = {0,0,0,0}, o3 = {0,0,0,0};

  f32x4 xc[4], xn[4];
  loadA(behB, r, kb, xc);
  int mc, mn = 0;
  {
    int t = r;
    mc = boolmask ? (int)maskB8[t] : maskB32[t];
  }

#pragma unroll 1
  for (int mt = 0; mt < MT; ++mt) {
    // prefetch next tile (T14: issue early, consume next iteration)
    if (mt + 1 < MT) {
      int tn = (mt + 1) * 16 + r;
      loadA(behB, tn, kb, xn);
      mn = (tn < T_LEN) ? (boolmask ? (int)maskB8[tn] : maskB32[tn]) : 0;
    }

    // convert A fragments: beh and beh*cand
    bf16x8 ab0, ab1, ap0, ap1;
#pragma unroll
    for (int i = 0; i < 4; ++i) {
      ab0[i]     = (__bf16)xc[0][i];
      ab0[4 + i] = (__bf16)xc[1][i];
      ab1[i]     = (__bf16)xc[2][i];
      ab1[4 + i] = (__bf16)xc[3][i];
      ap0[i]     = (__bf16)(xc[0][i] * c0a[i]);
      ap0[4 + i] = (__bf16)(xc[1][i] * c0b[i]);
      ap1[i]     = (__bf16)(xc[2][i] * c1a[i]);
      ap1[4 + i] = (__bf16)(xc[3][i] * c1b[i]);
    }

    // ---- layer 1: 4 n-tiles x K=128 ----
#pragma unroll
    for (int nt = 0; nt < 4; ++nt) {
      int j = nt * 16 + r;
      int jb = j * 256;
      int jx = (j & 7) << 4;
      bf16x8 b0 = *(const bf16x8*)(s.w1T + ((jb + (kb +  0) * 2) ^ jx));
      bf16x8 b1 = *(const bf16x8*)(s.w1T + ((jb + (kb + 32) * 2) ^ jx));
      bf16x8 b2 = *(const bf16x8*)(s.w1T + ((jb + (kb + 64) * 2) ^ jx));
      bf16x8 b3 = *(const bf16x8*)(s.w1T + ((jb + (kb + 96) * 2) ^ jx));
      f32x4 acc = {0.f, 0.f, 0.f, 0.f};
      acc = __builtin_amdgcn_mfma_f32_16x16x32_bf16(ab0, b0, acc, 0, 0, 0);
      acc = __builtin_amdgcn_mfma_f32_16x16x32_bf16(ab1, b1, acc, 0, 0, 0);
      acc = __builtin_amdgcn_mfma_f32_16x16x32_bf16(ap0, b2, acc, 0, 0, 0);
      acc = __builtin_amdgcn_mfma_f32_16x16x32_bf16(ap1, b3, acc, 0, 0, 0);
#pragma unroll
      for (int i = 0; i < 4; ++i) {
        float h = acc[i] + bias_nt[nt];
        h = (h >= 0.f) ? h : al1 * h;
        int ro = g * 4 + i;
        *(__bf16*)(s.h1T[wv] + ((ro * 128 + j * 2) ^ ((ro & 7) << 4))) = (__bf16)h;
      }
    }

    // ---- layer 2 (K=64, N=32) + layer-3 dot ----
    bf16x8 a2_0 = *(const bf16x8*)(s.h1T[wv] + ((r * 128 + (kb +  0) * 2) ^ ((r & 7) << 4)));
    bf16x8 a2_1 = *(const bf16x8*)(s.h1T[wv] + ((r * 128 + (kb + 32) * 2) ^ ((r & 7) << 4)));
    f32x4 acc20 = {0.f, 0.f, 0.f, 0.f}, acc21 = {0.f, 0.f, 0.f, 0.f};
    acc20 = __builtin_amdgcn_mfma_f32_16x16x32_bf16(a2_0, B2[0][0], acc20, 0, 0, 0);
    acc20 = __builtin_amdgcn_mfma_f32_16x16x32_bf16(a2_1, B2[0][1], acc20, 0, 0, 0);
    acc21 = __builtin_amdgcn_mfma_f32_16x16x32_bf16(a2_0, B2[1][0], acc21, 0, 0, 0);
    acc21 = __builtin_amdgcn_mfma_f32_16x16x32_bf16(a2_1, B2[1][1], acc21, 0, 0, 0);
    f32x4 q;
#pragma unroll
    for (int i = 0; i < 4; ++i) {
      float h0 = acc20[i] + b2v0; h0 = (h0 >= 0.f) ? h0 : al2 * h0;
      float h1 = acc21[i] + b2v1; h1 = (h1 >= 0.f) ? h1 : al2 * h1;
      q[i] = h0 * w3v0 + h1 * w3v1;
    }
#pragma unroll
    for (int off = 1; off < 16; off <<= 1)
#pragma unroll
      for (int i = 0; i < 4; ++i) q[i] += __shfl_xor(q[i], off);
    if (r == 0) {
#pragma unroll
      for (int i = 0; i < 4; ++i) s.wts16[wv][g * 4 + i] = q[i];
    }
    float l = s.wts16[wv][r];     // logit for this lane's row (same-wave LDS)

    // ---- online softmax + fused weighted accumulation ----
    bool valid = ((mt * 16 + r) < T_LEN) && (mc != 0);
    float lv = valid ? l : -__builtin_inff();
    float tmax = lv;
#pragma unroll
    for (int off = 1; off < 16; off <<= 1) tmax = fmaxf(tmax, __shfl_xor(tmax, off));
    float mnew = fmaxf(mrun, tmax);
    if (mnew > mrun) {            // wave-uniform; also guards -inf NaN
      float f = __expf(mrun - mnew);
      srun *= f;
#pragma unroll
      for (int i = 0; i < 4; ++i) { o0[i] *= f; o1[i] *= f; o2[i] *= f; o3[i] *= f; }
      mrun = mnew;
    }
    float e = valid ? __expf(lv - mrun) : 0.f;
    srun += e;
#pragma unroll
    for (int i = 0; i < 4; ++i) {
      o0[i] += e * xc[0][i];
      o1[i] += e * xc[1][i];
      o2[i] += e * xc[2][i];
      o3[i] += e * xc[3][i];
    }

    // rotate prefetch buffers
#pragma unroll
    for (int i = 0; i < 4; ++i) xc[i] = xn[i];
    mc = mn;
  }

  // ---- epilogue: reduce over the 16 rows held across the 16-lane group ----
#pragma unroll
  for (int off = 1; off < 16; off <<= 1) {
#pragma unroll
    for (int i = 0; i < 4; ++i) {
      o0[i] += __shfl_xor(o0[i], off);
      o1[i] += __shfl_xor(o1[i], off);
      o2[i] += __shfl_xor(o2[i], off);
      o3[i] += __shfl_xor(o3[i], off);
    }
    srun += __shfl_xor(srun, off);
  }
  if (r == 0) {
    *(f32x4*)&s.outL[wv][kb]      = o0;
    *(f32x4*)&s.outL[wv][kb + 4]  = o1;
    *(f32x4*)&s.outL[wv][kb + 32] = o2;
    *(f32x4*)&s.outL[wv][kb + 36] = o3;
  }
  float res = s.outL[wv][lane] / srun;   // srun uniform across wave
  outG[(size_t)b * 64 + lane] = res;
}

extern "C" void kernel_launch(void* const* d_in, const int* in_sizes, int n_in,
                              void* d_out, int out_size, void* d_ws, size_t ws_size,
                              hipStream_t stream) {
  (void)n_in; (void)d_ws; (void)ws_size; (void)out_size;
  const float* beh  = (const float*)d_in[0];
  const float* cand = (const float*)d_in[1];
  const int*   mask = (const int*)d_in[2];
  const float* W1   = (const float*)d_in[3];
  const float* b1   = (const float*)d_in[4];
  const float* a1   = (const float*)d_in[5];
  const float* W2   = (const float*)d_in[6];
  const float* b2   = (const float*)d_in[7];
  const float* a2   = (const float*)d_in[8];
  const float* W3   = (const float*)d_in[9];
  const float* b3   = (const float*)d_in[10];
  int B = in_sizes[1] / 64;   // 4096
  int grid = B / 4;           // one wave per batch row, 4 rows per block
  lau_kernel<<<grid, 256, 0, stream>>>(beh, cand, mask, W1, b1, a1, W2, b2, a2, W3, b3,
                                       (float*)d_out);
}

// Round 3
// 57.280 us; speedup vs baseline: 3.3407x; 1.8543x over previous
//
#include <hip/hip_runtime.h>
#include <hip/hip_bf16.h>

#define T_LEN 200
#define MT    13          // ceil(200/16)

typedef __bf16 bf16x8 __attribute__((ext_vector_type(8)));
typedef __bf16 bf16x4 __attribute__((ext_vector_type(4)));
typedef float  f32x4  __attribute__((ext_vector_type(4)));

#if __has_builtin(__builtin_amdgcn_mfma_f32_16x16x16_bf16)
#define MFMA16(a, b, c) __builtin_amdgcn_mfma_f32_16x16x16_bf16((a), (b), (c), 0, 0, 0)
#elif __has_builtin(__builtin_amdgcn_mfma_f32_16x16x16bf16_1k)
#define MFMA16(a, b, c) __builtin_amdgcn_mfma_f32_16x16x16bf16_1k((a), (b), (c), 0, 0, 0)
#else
static __device__ __forceinline__ f32x4 mfma16_asm(bf16x4 a, bf16x4 b, f32x4 c) {
  asm("v_mfma_f32_16x16x16_bf16 %0, %1, %2, %0" : "+v"(c) : "v"(a), "v"(b));
  return c;
}
#define MFMA16(a, b, c) mfma16_asm((a), (b), (c))
#endif

#define MFMA32(a, b, c) __builtin_amdgcn_mfma_f32_16x16x32_bf16((a), (b), (c), 0, 0, 0)

// LDS: prologue-only. stride 144B (9*16) => fragment reads are 2-way-max on banks (free).
struct __align__(16) Smem {
  unsigned char w1ac[64 * 144];   // [j][d] bf16: W1a+W1c (transposed)
  unsigned char w1d [64 * 144];   // [j][d] bf16: W1d     (transposed)
  float wdiff[64][64];            // [d][j] f32: W1b - W1c (for exact f32 bias)
  float candL[4][64];
};

__device__ __forceinline__ void loadA(const float* __restrict__ behB, int t, int kb,
                                      f32x4* x) {
  if (t < T_LEN) {
    const float* p = behB + (size_t)t * 64 + kb;
    x[0] = *(const f32x4*)p;
    x[1] = *(const f32x4*)(p + 4);
    x[2] = *(const f32x4*)(p + 32);
    x[3] = *(const f32x4*)(p + 36);
  } else {
    x[0] = f32x4{0.f, 0.f, 0.f, 0.f};
    x[1] = f32x4{0.f, 0.f, 0.f, 0.f};
    x[2] = f32x4{0.f, 0.f, 0.f, 0.f};
    x[3] = f32x4{0.f, 0.f, 0.f, 0.f};
  }
}

__global__ __launch_bounds__(256, 3) void lau_kernel(
    const float* __restrict__ behG, const float* __restrict__ candG,
    const int*  __restrict__ maskG,
    const float* __restrict__ W1g, const float* __restrict__ b1g, const float* __restrict__ a1g,
    const float* __restrict__ W2g, const float* __restrict__ b2g, const float* __restrict__ a2g,
    const float* __restrict__ W3g, const float* __restrict__ b3g,
    float* __restrict__ outG)
{
  __shared__ Smem s;
  const int tid  = threadIdx.x;
  const int lane = tid & 63;
  const int wv   = tid >> 6;
  const int b    = blockIdx.x * 4 + wv;

  // ---- cooperative staging (one barrier in the whole kernel) ----
  for (int idx = tid; idx < 4096; idx += 256) {
    int j = idx & 63, d = idx >> 6;            // lanes: consecutive j -> coalesced reads
    float ac = W1g[d * 64 + j] + W1g[(128 + d) * 64 + j];
    float dd = W1g[(192 + d) * 64 + j];
    *(__bf16*)(s.w1ac + j * 144 + d * 2) = (__bf16)ac;
    *(__bf16*)(s.w1d  + j * 144 + d * 2) = (__bf16)dd;
    s.wdiff[d][j] = W1g[(64 + d) * 64 + j] - W1g[(128 + d) * 64 + j];
  }
  s.candL[wv][lane] = candG[(size_t)b * 64 + lane];
  __syncthreads();
  // ---- waves fully independent below ----

  const int r  = lane & 15;
  const int g  = lane >> 4;
  const int kb = g * 8;

  const bool boolmask = (__ballot(((const unsigned int*)maskG)[lane] > 1u) != 0ull);

  // exact f32 bias: b1 + cand @ (W1b - W1c)
  float biasv = b1g[lane];
#pragma unroll 8
  for (int d = 0; d < 64; ++d)
    biasv += s.candL[wv][d] * s.wdiff[d][lane];

  f32x4 bj4[4];
#pragma unroll
  for (int jt = 0; jt < 4; ++jt)
#pragma unroll
    for (int i = 0; i < 4; ++i)
      bj4[jt][i] = __shfl(biasv, jt * 16 + g * 4 + i);   // bias for row j=jt*16+g*4+i

  // cand chunks for this lane's d-columns
  const f32x4 c0a = *(const f32x4*)&s.candL[wv][kb];
  const f32x4 c0b = *(const f32x4*)&s.candL[wv][kb + 4];
  const f32x4 c1a = *(const f32x4*)&s.candL[wv][kb + 32];
  const f32x4 c1b = *(const f32x4*)&s.candL[wv][kb + 36];

  // build loop-invariant layer-1 A-fragments: W1eff^T[j][d] = (W1a+W1c) + cand_d*W1d
  bf16x8 A1[4][2];
#pragma unroll
  for (int jt = 0; jt < 4; ++jt) {
#pragma unroll
    for (int kc = 0; kc < 2; ++kc) {
      const int rowoff = (jt * 16 + r) * 144 + kc * 64 + g * 16;
      bf16x8 ac = *(const bf16x8*)(s.w1ac + rowoff);
      bf16x8 dd = *(const bf16x8*)(s.w1d  + rowoff);
      f32x4 cA = (kc == 0) ? c0a : c1a;
      f32x4 cB = (kc == 0) ? c0b : c1b;
      bf16x8 o;
#pragma unroll
      for (int e = 0; e < 4; ++e) {
        o[e]     = (__bf16)((float)ac[e]     + cA[e] * (float)dd[e]);
        o[4 + e] = (__bf16)((float)ac[4 + e] + cB[e] * (float)dd[4 + e]);
      }
      A1[jt][kc] = o;
    }
  }

  // layer-2 B fragments (16x16x16 layout): B2f[nt][c][i] = W2[c*16+g*4+i][nt*16+r]
  bf16x4 B2f[2][4];
#pragma unroll
  for (int nt = 0; nt < 2; ++nt)
#pragma unroll
    for (int c = 0; c < 4; ++c)
#pragma unroll
      for (int i = 0; i < 4; ++i)
        B2f[nt][c][i] = (__bf16)W2g[(c * 16 + g * 4 + i) * 32 + nt * 16 + r];

  const float al1 = a1g[0];
  const float al2 = a2g[0];
  const float b2v0 = b2g[r],      b2v1 = b2g[16 + r];
  const float w3v0 = W3g[r],      w3v1 = W3g[16 + r];
  (void)b3g;  // uniform additive bias cancels in softmax

  const float* behB = behG + (size_t)b * T_LEN * 64;
  const unsigned char* maskB8 = (const unsigned char*)maskG + (size_t)b * T_LEN;
  const int* maskB32 = maskG + (size_t)b * T_LEN;

  float mrun = -__builtin_inff();
  float srun = 0.f;
  f32x4 o0 = {0,0,0,0}, o1 = {0,0,0,0}, o2 = {0,0,0,0}, o3 = {0,0,0,0};

  f32x4 xc[4], xn[4];
  loadA(behB, r, kb, xc);
  int mc = boolmask ? (int)maskB8[r] : maskB32[r];
  int mn = 0;

#pragma unroll 1
  for (int mt = 0; mt < MT; ++mt) {
    // prefetch next tile
    if (mt + 1 < MT) {
      int tn = (mt + 1) * 16 + r;
      loadA(behB, tn, kb, xn);
      mn = (tn < T_LEN) ? (boolmask ? (int)maskB8[tn] : maskB32[tn]) : 0;
    }

    // B-fragment (beh row) in bf16
    bf16x8 ab0, ab1;
#pragma unroll
    for (int i = 0; i < 4; ++i) {
      ab0[i]     = (__bf16)xc[0][i];
      ab0[4 + i] = (__bf16)xc[1][i];
      ab1[i]     = (__bf16)xc[2][i];
      ab1[4 + i] = (__bf16)xc[3][i];
    }

    // ---- layer 1 (swapped: D[j][t]), bias as MFMA C-in; output feeds layer-2 A directly
    bf16x4 a2f[4];
#pragma unroll
    for (int jt = 0; jt < 4; ++jt) {
      f32x4 acc = MFMA32(A1[jt][0], ab0, bj4[jt]);
      acc = MFMA32(A1[jt][1], ab1, acc);
#pragma unroll
      for (int i = 0; i < 4; ++i) {
        float h = acc[i];
        h = (h >= 0.f) ? h : al1 * h;
        a2f[jt][i] = (__bf16)h;
      }
    }

    // ---- layer 2: 8x mfma 16x16x16, register-chained ----
    f32x4 acc20 = {0,0,0,0}, acc21 = {0,0,0,0};
#pragma unroll
    for (int c = 0; c < 4; ++c) acc20 = MFMA16(a2f[c], B2f[0][c], acc20);
#pragma unroll
    for (int c = 0; c < 4; ++c) acc21 = MFMA16(a2f[c], B2f[1][c], acc21);

    // ---- layer 3 dot + reduce over the 32 j2 (r-lanes) ----
    f32x4 q;
#pragma unroll
    for (int i = 0; i < 4; ++i) {
      float h0 = acc20[i] + b2v0; h0 = (h0 >= 0.f) ? h0 : al2 * h0;
      float h1 = acc21[i] + b2v1; h1 = (h1 >= 0.f) ? h1 : al2 * h1;
      q[i] = h0 * w3v0 + h1 * w3v1;
    }
#pragma unroll
    for (int off = 1; off < 16; off <<= 1)
#pragma unroll
      for (int i = 0; i < 4; ++i) q[i] += __shfl_xor(q[i], off);
    // q[i] = logit[t = mt*16 + g*4 + i], replicated across r

    // broadcast logit for t = r to this lane
    const int srcl = (r >> 2) << 4;
    float f0 = __shfl(q[0], srcl);
    float f1 = __shfl(q[1], srcl);
    float f2 = __shfl(q[2], srcl);
    float f3 = __shfl(q[3], srcl);
    float q01 = (r & 1) ? f1 : f0;
    float q23 = (r & 1) ? f3 : f2;
    float qt  = (r & 2) ? q23 : q01;

    const bool valid = ((mt * 16 + r) < T_LEN) && (mc != 0);
    float lvt = valid ? qt : -__builtin_inff();
    float tm = lvt;
#pragma unroll
    for (int off = 1; off < 16; off <<= 1) tm = fmaxf(tm, __shfl_xor(tm, off));

    // T13 defer-max: rescale only when the max moved by > 8
    if (tm > mrun + 8.f) {           // wave-uniform
      float fs = __expf(mrun - tm);  // mrun=-inf -> fs=0 (correct first-tile behavior)
      srun *= fs;
#pragma unroll
      for (int i = 0; i < 4; ++i) { o0[i] *= fs; o1[i] *= fs; o2[i] *= fs; o3[i] *= fs; }
      mrun = tm;
    }
    float et = valid ? __expf(lvt - mrun) : 0.f;
    srun += et;
#pragma unroll
    for (int i = 0; i < 4; ++i) {
      o0[i] += et * xc[0][i];
      o1[i] += et * xc[1][i];
      o2[i] += et * xc[2][i];
      o3[i] += et * xc[3][i];
    }

#pragma unroll
    for (int i = 0; i < 4; ++i) xc[i] = xn[i];
    mc = mn;
  }

  // ---- epilogue: reduce over r (the 16 t-rows per iteration slot) ----
#pragma unroll
  for (int off = 1; off < 16; off <<= 1) {
#pragma unroll
    for (int i = 0; i < 4; ++i) {
      o0[i] += __shfl_xor(o0[i], off);
      o1[i] += __shfl_xor(o1[i], off);
      o2[i] += __shfl_xor(o2[i], off);
      o3[i] += __shfl_xor(o3[i], off);
    }
    srun += __shfl_xor(srun, off);
  }
  if (r == 0) {
    float inv = 1.f / srun;
    float* po = outG + (size_t)b * 64 + kb;
#pragma unroll
    for (int i = 0; i < 4; ++i) {
      o0[i] *= inv; o1[i] *= inv; o2[i] *= inv; o3[i] *= inv;
    }
    *(f32x4*)(po)      = o0;
    *(f32x4*)(po + 4)  = o1;
    *(f32x4*)(po + 32) = o2;
    *(f32x4*)(po + 36) = o3;
  }
}

extern "C" void kernel_launch(void* const* d_in, const int* in_sizes, int n_in,
                              void* d_out, int out_size, void* d_ws, size_t ws_size,
                              hipStream_t stream) {
  (void)n_in; (void)d_ws; (void)ws_size; (void)out_size;
  const float* beh  = (const float*)d_in[0];
  const float* cand = (const float*)d_in[1];
  const int*   mask = (const int*)d_in[2];
  const float* W1   = (const float*)d_in[3];
  const float* b1   = (const float*)d_in[4];
  const float* a1   = (const float*)d_in[5];
  const float* W2   = (const float*)d_in[6];
  const float* b2   = (const float*)d_in[7];
  const float* a2   = (const float*)d_in[8];
  const float* W3   = (const float*)d_in[9];
  const float* b3   = (const float*)d_in[10];
  int B = in_sizes[1] / 64;   // 4096
  int grid = B / 4;           // one wave per batch row, 4 rows per block
  lau_kernel<<<grid, 256, 0, stream>>>(beh, cand, mask, W1, b1, a1, W2, b2, a2, W3, b3,
                                       (float*)d_out);
}